// Round 15
// baseline (309.615 us; speedup 1.0000x reference)
//
#include <hip/hip_runtime.h>
#include <hip/hip_bf16.h>

#define NN 50000
#define EE 800000
#define FF 144
#define NBLK 196   // ceil(NN/256)

typedef __hip_bfloat16 bf16;
typedef __attribute__((ext_vector_type(8))) short short8;
typedef __attribute__((ext_vector_type(4))) float floatx4;

__device__ inline float blo(unsigned x) { return __uint_as_float(x << 16); }
__device__ inline float bhi(unsigned x) { return __uint_as_float(x & 0xffff0000u); }

// ---------------- edge_index int64-layout detection ----------------

__global__ void detect_k(const int* __restrict__ ei, int* __restrict__ flag) {
    __shared__ int nz;
    if (threadIdx.x == 0) nz = 0;
    __syncthreads();
    if (ei[2 * threadIdx.x + 1] != 0) atomicAdd(&nz, 1);
    __syncthreads();
    if (threadIdx.x == 0) *flag = (nz == 0) ? 1 : 0;
}

__device__ inline void load_edge(const int* ei, int e, int flag, int& r, int& c) {
    if (flag) { r = ei[2 * e]; c = ei[2 * EE + 2 * e]; }
    else      { r = ei[e];     c = ei[EE + e]; }
}

// ---------------- x fp32 -> bf16 ----------------

__global__ void cvt_k(const float* __restrict__ x, bf16* __restrict__ xb) {
    int t = blockIdx.x * 256 + threadIdx.x;
    if (t >= NN * FF) return;
    xb[t] = (bf16)x[t];
}

// ---------------- W fp32 (K,i,o) -> bf16 transposed padded image wtb[ph][o][i] ----------------

__global__ void cvtw_k(const float* __restrict__ wt, short* __restrict__ wtb) {
    int t = blockIdx.x * 256 + threadIdx.x;
    if (t >= 3 * FF * 168) return;
    int ph = t / (FF * 168);
    int rem = t - ph * FF * 168;
    int o = rem / 168;
    int i = rem - o * 168;
    short v = 0;
    if (i < FF) {
        bf16 b = (bf16)wt[ph * FF * FF + i * FF + o];
        v = *(const short*)&b;
    }
    wtb[t] = v;
}

// ---------------- graph preprocessing ----------------

__global__ void hist_k(const int* __restrict__ ei, int* __restrict__ cnt,
                       const int* __restrict__ flagp) {
    int flag = *flagp;
    int e = blockIdx.x * 256 + threadIdx.x;
    if (e >= EE) return;
    int r, c; load_edge(ei, e, flag, r, c);
    if (r != c) atomicAdd(&cnt[r], 1);
}

__global__ void dinv_k(const int* __restrict__ cnt, float* __restrict__ dinv) {
    int i = blockIdx.x * 256 + threadIdx.x;
    if (i >= NN) return;
    int c = cnt[i];
    dinv[i] = c > 0 ? rsqrtf((float)c) : 0.f;
}

// ---------------- multi-block exclusive scan: cnt -> rowptr ----------------

__global__ void scan1_k(const int* __restrict__ cnt, int* __restrict__ rowptr,
                        int* __restrict__ bsum) {
    __shared__ int wsum[4], woff[4];
    int b = blockIdx.x, tid = threadIdx.x;
    int wv = tid >> 6, ln = tid & 63;
    int i = b * 256 + tid;
    int v = (i < NN) ? cnt[i] : 0;
    int x = v;
    #pragma unroll
    for (int off = 1; off < 64; off <<= 1) {
        int t = __shfl_up(x, off, 64);
        if (ln >= off) x += t;
    }
    if (ln == 63) wsum[wv] = x;
    __syncthreads();
    if (tid == 0) {
        int s = 0;
        #pragma unroll
        for (int j = 0; j < 4; ++j) { woff[j] = s; s += wsum[j]; }
        bsum[b] = s;
    }
    __syncthreads();
    if (i < NN) rowptr[i] = woff[wv] + (x - v);
}

__global__ void scan2_k(int* __restrict__ bsum, int* __restrict__ rowptr) {
    __shared__ int wsum[4], woff[4];
    int tid = threadIdx.x;
    int wv = tid >> 6, ln = tid & 63;
    int v = (tid < NBLK) ? bsum[tid] : 0;
    int x = v;
    #pragma unroll
    for (int off = 1; off < 64; off <<= 1) {
        int t = __shfl_up(x, off, 64);
        if (ln >= off) x += t;
    }
    if (ln == 63) wsum[wv] = x;
    __syncthreads();
    if (tid == 0) {
        int s = 0;
        #pragma unroll
        for (int j = 0; j < 4; ++j) { woff[j] = s; s += wsum[j]; }
        rowptr[NN] = s;
    }
    __syncthreads();
    if (tid < NBLK) bsum[tid] = woff[wv] + (x - v);
}

__global__ void scan3_k(int* __restrict__ rowptr, const int* __restrict__ bsum) {
    int b = blockIdx.x;
    int i = b * 256 + threadIdx.x;
    if (i < NN) rowptr[i] += bsum[b];
}

// ---------------- scatter: packed (col, lap) int2 per edge ----------------

__global__ void scatter_k(const int* __restrict__ ei, const float* __restrict__ w,
                          const float* __restrict__ dinv, const int* __restrict__ rowptr,
                          int* __restrict__ fill, int2* __restrict__ pairs,
                          const int* __restrict__ flagp) {
    int flag = *flagp;
    int e = blockIdx.x * 256 + threadIdx.x;
    if (e >= EE) return;
    int r, c; load_edge(ei, e, flag, r, c);
    if (r == c) return;
    int pos = rowptr[r] + atomicAdd(&fill[r], 1);
    int2 pr;
    pr.x = c;
    pr.y = __float_as_int(-dinv[r] * dinv[c] * w[e]);
    pairs[pos] = pr;
}

// ---------------- SpMM 16-wide: 9 threads/node, 2x uint4 gather/edge, unroll x2 ----------------

__device__ inline void fma16(float* a, float l, uint4 u0, uint4 u1) {
    a[0]  = fmaf(l, blo(u0.x), a[0]);   a[1]  = fmaf(l, bhi(u0.x), a[1]);
    a[2]  = fmaf(l, blo(u0.y), a[2]);   a[3]  = fmaf(l, bhi(u0.y), a[3]);
    a[4]  = fmaf(l, blo(u0.z), a[4]);   a[5]  = fmaf(l, bhi(u0.z), a[5]);
    a[6]  = fmaf(l, blo(u0.w), a[6]);   a[7]  = fmaf(l, bhi(u0.w), a[7]);
    a[8]  = fmaf(l, blo(u1.x), a[8]);   a[9]  = fmaf(l, bhi(u1.x), a[9]);
    a[10] = fmaf(l, blo(u1.y), a[10]);  a[11] = fmaf(l, bhi(u1.y), a[11]);
    a[12] = fmaf(l, blo(u1.z), a[12]);  a[13] = fmaf(l, bhi(u1.z), a[13]);
    a[14] = fmaf(l, blo(u1.w), a[14]);  a[15] = fmaf(l, bhi(u1.w), a[15]);
}

template <int MODE>
__global__ void spmm_k(const bf16* __restrict__ v, const bf16* __restrict__ x0,
                       const int* __restrict__ rowptr, const int2* __restrict__ pairs,
                       bf16* __restrict__ y) {
    int t = blockIdx.x * 256 + threadIdx.x;
    if (t >= NN * 9) return;
    int i = t / 9;
    int f16 = (t - i * 9) * 16;
    const unsigned short* vp = (const unsigned short*)v + f16;

    float a[16];
    #pragma unroll
    for (int j = 0; j < 16; ++j) a[j] = 0.f;

    int s = rowptr[i], e = rowptr[i + 1];
    int p = s;
    for (; p + 1 < e; p += 2) {
        int2 pr0 = pairs[p], pr1 = pairs[p + 1];
        float l0 = __int_as_float(pr0.y), l1 = __int_as_float(pr1.y);
        const uint4* g0 = (const uint4*)(vp + pr0.x * FF);
        const uint4* g1 = (const uint4*)(vp + pr1.x * FF);
        uint4 u00 = g0[0], u01 = g0[1];
        uint4 u10 = g1[0], u11 = g1[1];
        fma16(a, l0, u00, u01);
        fma16(a, l1, u10, u11);
    }
    if (p < e) {
        int2 pr = pairs[p];
        float l = __int_as_float(pr.y);
        const uint4* g = (const uint4*)(vp + pr.x * FF);
        uint4 u0 = g[0], u1 = g[1];
        fma16(a, l, u0, u1);
    }

    if (MODE == 1) {
        const uint4* xq = (const uint4*)((const unsigned short*)x0 + i * FF + f16);
        uint4 u0 = xq[0], u1 = xq[1];
        a[0]  = 2.f * a[0]  - blo(u0.x);  a[1]  = 2.f * a[1]  - bhi(u0.x);
        a[2]  = 2.f * a[2]  - blo(u0.y);  a[3]  = 2.f * a[3]  - bhi(u0.y);
        a[4]  = 2.f * a[4]  - blo(u0.z);  a[5]  = 2.f * a[5]  - bhi(u0.z);
        a[6]  = 2.f * a[6]  - blo(u0.w);  a[7]  = 2.f * a[7]  - bhi(u0.w);
        a[8]  = 2.f * a[8]  - blo(u1.x);  a[9]  = 2.f * a[9]  - bhi(u1.x);
        a[10] = 2.f * a[10] - blo(u1.y);  a[11] = 2.f * a[11] - bhi(u1.y);
        a[12] = 2.f * a[12] - blo(u1.z);  a[13] = 2.f * a[13] - bhi(u1.z);
        a[14] = 2.f * a[14] - blo(u1.w);  a[15] = 2.f * a[15] - bhi(u1.w);
    }

    unsigned short rs[16];
    #pragma unroll
    for (int j = 0; j < 16; ++j) {
        bf16 b = (bf16)a[j];
        rs[j] = *(unsigned short*)&b;
    }
    uint4* yq = (uint4*)((unsigned short*)y + i * FF + f16);
    yq[0] = ((uint4*)rs)[0];
    yq[1] = ((uint4*)rs)[1];
}

// ---------------- fused MFMA GEMM (unchanged from r13/r14 passing version) ----------------

__global__ __launch_bounds__(256)
void gemm_fused(const bf16* __restrict__ A0, const bf16* __restrict__ A1,
                const bf16* __restrict__ A2, const short* __restrict__ wtb,
                const float* __restrict__ bias, float* __restrict__ out) {
    __shared__ __align__(16) short Wt[144 * 168];
    int tid = threadIdx.x;
    int wv = tid >> 6, ln = tid & 63;
    int m16 = ln & 15, quad = ln >> 4;
    int rowBase = blockIdx.x * 64 + wv * 16;
    int row = rowBase + m16;

    const bf16* const srcs[3] = {A0, A1, A2};
    const short8 zero8 = {0, 0, 0, 0, 0, 0, 0, 0};

    floatx4 acc[9];
    #pragma unroll
    for (int q = 0; q < 9; ++q) acc[q] = (floatx4){0.f, 0.f, 0.f, 0.f};

    #pragma unroll
    for (int ph = 0; ph < 3; ++ph) {
        __syncthreads();
        const uint4* Wg = (const uint4*)(wtb + ph * 144 * 168);   // 3024 uint4
        uint4* Wl = (uint4*)Wt;
        #pragma unroll
        for (int q = 0; q < 12; ++q) {
            int idx = q * 256 + tid;
            if (idx < 3024) Wl[idx] = Wg[idx];
        }
        __syncthreads();

        const bf16* A = srcs[ph];
        short8 a[5];
        #pragma unroll
        for (int kt = 0; kt < 5; ++kt) {
            int k0 = kt * 32 + quad * 8;
            if (k0 < FF && row < NN)
                a[kt] = *(const short8*)((const short*)A + row * FF + k0);
            else
                a[kt] = zero8;
        }

        #pragma unroll
        for (int nt = 0; nt < 9; ++nt) {
            #pragma unroll
            for (int kt = 0; kt < 5; ++kt) {
                short8 b = *(const short8*)&Wt[(nt * 16 + m16) * 168 + kt * 32 + quad * 8];
                acc[nt] = __builtin_amdgcn_mfma_f32_16x16x32_bf16(a[kt], b, acc[nt], 0, 0, 0);
            }
        }
    }

    int rowc = rowBase + quad * 4;
    #pragma unroll
    for (int nt = 0; nt < 9; ++nt) {
        int col = nt * 16 + m16;
        float bs = bias[col];
        #pragma unroll
        for (int r = 0; r < 4; ++r) {
            int rr = rowc + r;
            if (rr < NN) out[rr * FF + col] = acc[nt][r] + bs;
        }
    }
}

// ---------------- launch ----------------

extern "C" void kernel_launch(void* const* d_in, const int* in_sizes, int n_in,
                              void* d_out, int out_size, void* d_ws, size_t ws_size,
                              hipStream_t stream) {
    int ix = -1, iei = -1, iew = -1, iwt = -1, ib = -1;
    for (int i = 0; i < n_in; ++i) {
        switch (in_sizes[i]) {
            case NN * FF:      if (ix  < 0) ix  = i; break;
            case 2 * EE:       if (iei < 0) iei = i; break;
            case EE:           if (iew < 0) iew = i; break;
            case 3 * FF * FF:  if (iwt < 0) iwt = i; break;
            case FF:           if (ib  < 0) ib  = i; break;
        }
    }
    if (ix < 0 || iei < 0 || iew < 0 || iwt < 0 || ib < 0) {
        ix = 0; iei = 1; iew = 2; iwt = 3; ib = 4;
    }
    const float* x    = (const float*)d_in[ix];
    const int*   ei   = (const int*)d_in[iei];
    const float* ew   = (const float*)d_in[iew];
    const float* wt   = (const float*)d_in[iwt];
    const float* bias = (const float*)d_in[ib];
    float* out = (float*)d_out;   // reference output dtype is float32

    char* p = (char*)d_ws;
    int*   cnt    = (int*)(p + 0);           // N ints
    int*   fill   = (int*)(p + 200000);      // N ints
    int*   rowptr = (int*)(p + 400000);      // N+1 ints
    float* dinv   = (float*)(p + 600016);    // N floats
    int2*  pairs  = (int2*)(p + 800016);     // E int2 (col, lap)
    bf16*  tx1    = (bf16*)(p + 7200016);
    bf16*  tx2    = (bf16*)(p + 21600016);
    short* wtb    = (short*)(p + 36000016);  // 3*144*168 shorts
    int*   bsum   = (int*)(p + 36200000);    // NBLK ints
    bf16*  xb     = (bf16*)(p + 64800016);
    int*   eflag  = (int*)(p + 79200016);

    if (ws_size < 79200032) return;

    hipMemsetAsync(d_ws, 0, 400000, stream);  // cnt + fill

    int ewGrid   = (NN * FF + 255) / 256;
    int spGrid   = (NN * 9 + 255) / 256;
    int gemmGrid = (NN + 63) / 64;
    int wGrid    = (3 * FF * 168 + 255) / 256;

    detect_k<<<1, 256, 0, stream>>>(ei, eflag);
    cvt_k<<<ewGrid, 256, 0, stream>>>(x, xb);
    cvtw_k<<<wGrid, 256, 0, stream>>>(wt, wtb);
    hist_k<<<(EE + 255) / 256, 256, 0, stream>>>(ei, cnt, eflag);
    dinv_k<<<(NN + 255) / 256, 256, 0, stream>>>(cnt, dinv);
    scan1_k<<<NBLK, 256, 0, stream>>>(cnt, rowptr, bsum);
    scan2_k<<<1, 256, 0, stream>>>(bsum, rowptr);
    scan3_k<<<NBLK, 256, 0, stream>>>(rowptr, bsum);
    scatter_k<<<(EE + 255) / 256, 256, 0, stream>>>(ei, ew, dinv, rowptr, fill, pairs, eflag);

    spmm_k<0><<<spGrid, 256, 0, stream>>>(xb, xb, rowptr, pairs, tx1);
    spmm_k<1><<<spGrid, 256, 0, stream>>>(tx1, xb, rowptr, pairs, tx2);
    gemm_fused<<<gemmGrid, 256, 0, stream>>>(xb, tx1, tx2, wtb, bias, out);
}

// Round 16
// 270.165 us; speedup vs baseline: 1.1460x; 1.1460x over previous
//
#include <hip/hip_runtime.h>
#include <hip/hip_bf16.h>

#define NN 50000
#define EE 800000
#define FF 144
#define NBLK 196   // ceil(NN/256)

typedef __hip_bfloat16 bf16;
typedef __attribute__((ext_vector_type(8))) short short8;
typedef __attribute__((ext_vector_type(4))) float floatx4;
typedef __attribute__((ext_vector_type(2))) float float2v;

__device__ inline float blo(unsigned x) { return __uint_as_float(x << 16); }
__device__ inline float bhi(unsigned x) { return __uint_as_float(x & 0xffff0000u); }

// ---- fp8 e4m3 pack/unpack (gfx950 OCP) ----
__device__ inline void dec4fma(float* a, float l, unsigned d) {
    float2v p0 = __builtin_amdgcn_cvt_pk_f32_fp8((int)d, false);
    float2v p1 = __builtin_amdgcn_cvt_pk_f32_fp8((int)d, true);
    a[0] = fmaf(l, p0.x, a[0]);
    a[1] = fmaf(l, p0.y, a[1]);
    a[2] = fmaf(l, p1.x, a[2]);
    a[3] = fmaf(l, p1.y, a[3]);
}
__device__ inline void fma16q(float* a, float l, uint4 u) {
    dec4fma(a + 0, l, u.x);
    dec4fma(a + 4, l, u.y);
    dec4fma(a + 8, l, u.z);
    dec4fma(a + 12, l, u.w);
}
__device__ inline unsigned enc4(float a, float b, float c, float d) {
    int w = __builtin_amdgcn_cvt_pk_fp8_f32(a, b, 0, false);
    w = __builtin_amdgcn_cvt_pk_fp8_f32(c, d, w, true);
    return (unsigned)w;
}

// ---------------- edge_index int64-layout detection ----------------

__global__ void detect_k(const int* __restrict__ ei, int* __restrict__ flag) {
    __shared__ int nz;
    if (threadIdx.x == 0) nz = 0;
    __syncthreads();
    if (ei[2 * threadIdx.x + 1] != 0) atomicAdd(&nz, 1);
    __syncthreads();
    if (threadIdx.x == 0) *flag = (nz == 0) ? 1 : 0;
}

__device__ inline void load_edge(const int* ei, int e, int flag, int& r, int& c) {
    if (flag) { r = ei[2 * e]; c = ei[2 * EE + 2 * e]; }
    else      { r = ei[e];     c = ei[EE + e]; }
}

// ---------------- x fp32 -> bf16 + fp8, 16 elements/thread ----------------

__global__ void cvt_k(const float* __restrict__ x, bf16* __restrict__ xb,
                      unsigned char* __restrict__ xq) {
    int t = blockIdx.x * 256 + threadIdx.x;
    if (t >= NN * FF / 16) return;
    const float4* xp = (const float4*)x + t * 4;
    float4 v0 = xp[0], v1 = xp[1], v2 = xp[2], v3 = xp[3];
    float f[16] = {v0.x, v0.y, v0.z, v0.w, v1.x, v1.y, v1.z, v1.w,
                   v2.x, v2.y, v2.z, v2.w, v3.x, v3.y, v3.z, v3.w};
    unsigned short hs[16];
    #pragma unroll
    for (int j = 0; j < 16; ++j) {
        bf16 b = (bf16)f[j];
        hs[j] = *(unsigned short*)&b;
    }
    uint4* xbq = (uint4*)xb + t * 2;
    xbq[0] = ((uint4*)hs)[0];
    xbq[1] = ((uint4*)hs)[1];
    uint4 q;
    q.x = enc4(f[0], f[1], f[2], f[3]);
    q.y = enc4(f[4], f[5], f[6], f[7]);
    q.z = enc4(f[8], f[9], f[10], f[11]);
    q.w = enc4(f[12], f[13], f[14], f[15]);
    ((uint4*)xq)[t] = q;
}

// ---------------- W fp32 (K,i,o) -> bf16 transposed padded image wtb[ph][o][i] ----------------

__global__ void cvtw_k(const float* __restrict__ wt, short* __restrict__ wtb) {
    int t = blockIdx.x * 256 + threadIdx.x;
    if (t >= 3 * FF * 168) return;
    int ph = t / (FF * 168);
    int rem = t - ph * FF * 168;
    int o = rem / 168;
    int i = rem - o * 168;
    short v = 0;
    if (i < FF) {
        bf16 b = (bf16)wt[ph * FF * FF + i * FF + o];
        v = *(const short*)&b;
    }
    wtb[t] = v;
}

// ---------------- graph preprocessing ----------------

__global__ void hist_k(const int* __restrict__ ei, int* __restrict__ cnt,
                       const int* __restrict__ flagp) {
    int flag = *flagp;
    int e = blockIdx.x * 256 + threadIdx.x;
    if (e >= EE) return;
    int r, c; load_edge(ei, e, flag, r, c);
    if (r != c) atomicAdd(&cnt[r], 1);
}

__global__ void dinv_k(const int* __restrict__ cnt, float* __restrict__ dinv) {
    int i = blockIdx.x * 256 + threadIdx.x;
    if (i >= NN) return;
    int c = cnt[i];
    dinv[i] = c > 0 ? rsqrtf((float)c) : 0.f;
}

// ---------------- multi-block exclusive scan: cnt -> rowptr ----------------

__global__ void scan1_k(const int* __restrict__ cnt, int* __restrict__ rowptr,
                        int* __restrict__ bsum) {
    __shared__ int wsum[4], woff[4];
    int b = blockIdx.x, tid = threadIdx.x;
    int wv = tid >> 6, ln = tid & 63;
    int i = b * 256 + tid;
    int v = (i < NN) ? cnt[i] : 0;
    int x = v;
    #pragma unroll
    for (int off = 1; off < 64; off <<= 1) {
        int t = __shfl_up(x, off, 64);
        if (ln >= off) x += t;
    }
    if (ln == 63) wsum[wv] = x;
    __syncthreads();
    if (tid == 0) {
        int s = 0;
        #pragma unroll
        for (int j = 0; j < 4; ++j) { woff[j] = s; s += wsum[j]; }
        bsum[b] = s;
    }
    __syncthreads();
    if (i < NN) rowptr[i] = woff[wv] + (x - v);
}

__global__ void scan2_k(int* __restrict__ bsum, int* __restrict__ rowptr) {
    __shared__ int wsum[4], woff[4];
    int tid = threadIdx.x;
    int wv = tid >> 6, ln = tid & 63;
    int v = (tid < NBLK) ? bsum[tid] : 0;
    int x = v;
    #pragma unroll
    for (int off = 1; off < 64; off <<= 1) {
        int t = __shfl_up(x, off, 64);
        if (ln >= off) x += t;
    }
    if (ln == 63) wsum[wv] = x;
    __syncthreads();
    if (tid == 0) {
        int s = 0;
        #pragma unroll
        for (int j = 0; j < 4; ++j) { woff[j] = s; s += wsum[j]; }
        rowptr[NN] = s;
    }
    __syncthreads();
    if (tid < NBLK) bsum[tid] = woff[wv] + (x - v);
}

__global__ void scan3_k(int* __restrict__ rowptr, const int* __restrict__ bsum) {
    int b = blockIdx.x;
    int i = b * 256 + threadIdx.x;
    if (i < NN) rowptr[i] += bsum[b];
}

// ---------------- scatter: packed (col, lap) int2 per edge ----------------

__global__ void scatter_k(const int* __restrict__ ei, const float* __restrict__ w,
                          const float* __restrict__ dinv, const int* __restrict__ rowptr,
                          int* __restrict__ fill, int2* __restrict__ pairs,
                          const int* __restrict__ flagp) {
    int flag = *flagp;
    int e = blockIdx.x * 256 + threadIdx.x;
    if (e >= EE) return;
    int r, c; load_edge(ei, e, flag, r, c);
    if (r == c) return;
    int pos = rowptr[r] + atomicAdd(&fill[r], 1);
    int2 pr;
    pr.x = c;
    pr.y = __float_as_int(-dinv[r] * dinv[c] * w[e]);
    pairs[pos] = pr;
}

// ---------------- SpMM fp8-gather: 9 threads/node, 1 uint4 (16 fp8) per edge ----------------
// MODE 0: y = spmm(vq), also emits fp8 copy yq for the next spmm.
// MODE 1: y = 2*spmm(vq) - x0 (x0 read bf16), no fp8 output.

template <int MODE>
__global__ void spmm_k(const unsigned char* __restrict__ vq, const bf16* __restrict__ x0,
                       const int* __restrict__ rowptr, const int2* __restrict__ pairs,
                       bf16* __restrict__ y, unsigned char* __restrict__ yq) {
    int t = blockIdx.x * 256 + threadIdx.x;
    if (t >= NN * 9) return;
    int i = t / 9;
    int fo = (t - i * 9) * 16;
    const unsigned char* vp = vq + fo;

    float a[16];
    #pragma unroll
    for (int j = 0; j < 16; ++j) a[j] = 0.f;

    int s = rowptr[i], e = rowptr[i + 1];
    int p = s;
    for (; p + 1 < e; p += 2) {
        int2 pr0 = pairs[p], pr1 = pairs[p + 1];
        uint4 u0 = *(const uint4*)(vp + pr0.x * FF);
        uint4 u1 = *(const uint4*)(vp + pr1.x * FF);
        float l0 = __int_as_float(pr0.y), l1 = __int_as_float(pr1.y);
        fma16q(a, l0, u0);
        fma16q(a, l1, u1);
    }
    if (p < e) {
        int2 pr = pairs[p];
        uint4 u = *(const uint4*)(vp + pr.x * FF);
        fma16q(a, __int_as_float(pr.y), u);
    }

    if (MODE == 1) {
        const uint4* xp = (const uint4*)((const unsigned short*)x0 + i * FF + fo);
        uint4 u0 = xp[0], u1 = xp[1];
        a[0]  = 2.f * a[0]  - blo(u0.x);  a[1]  = 2.f * a[1]  - bhi(u0.x);
        a[2]  = 2.f * a[2]  - blo(u0.y);  a[3]  = 2.f * a[3]  - bhi(u0.y);
        a[4]  = 2.f * a[4]  - blo(u0.z);  a[5]  = 2.f * a[5]  - bhi(u0.z);
        a[6]  = 2.f * a[6]  - blo(u0.w);  a[7]  = 2.f * a[7]  - bhi(u0.w);
        a[8]  = 2.f * a[8]  - blo(u1.x);  a[9]  = 2.f * a[9]  - bhi(u1.x);
        a[10] = 2.f * a[10] - blo(u1.y);  a[11] = 2.f * a[11] - bhi(u1.y);
        a[12] = 2.f * a[12] - blo(u1.z);  a[13] = 2.f * a[13] - bhi(u1.z);
        a[14] = 2.f * a[14] - blo(u1.w);  a[15] = 2.f * a[15] - bhi(u1.w);
    }

    unsigned short hs[16];
    #pragma unroll
    for (int j = 0; j < 16; ++j) {
        bf16 b = (bf16)a[j];
        hs[j] = *(unsigned short*)&b;
    }
    uint4* yp = (uint4*)((unsigned short*)y + i * FF + fo);
    yp[0] = ((uint4*)hs)[0];
    yp[1] = ((uint4*)hs)[1];

    if (MODE == 0) {
        uint4 q;
        q.x = enc4(a[0], a[1], a[2], a[3]);
        q.y = enc4(a[4], a[5], a[6], a[7]);
        q.z = enc4(a[8], a[9], a[10], a[11]);
        q.w = enc4(a[12], a[13], a[14], a[15]);
        *(uint4*)(yq + i * FF + fo) = q;
    }
}

// ---------------- fused MFMA GEMM (unchanged from r13-r15 passing version) ----------------

__global__ __launch_bounds__(256)
void gemm_fused(const bf16* __restrict__ A0, const bf16* __restrict__ A1,
                const bf16* __restrict__ A2, const short* __restrict__ wtb,
                const float* __restrict__ bias, float* __restrict__ out) {
    __shared__ __align__(16) short Wt[144 * 168];
    int tid = threadIdx.x;
    int wv = tid >> 6, ln = tid & 63;
    int m16 = ln & 15, quad = ln >> 4;
    int rowBase = blockIdx.x * 64 + wv * 16;
    int row = rowBase + m16;

    const bf16* const srcs[3] = {A0, A1, A2};
    const short8 zero8 = {0, 0, 0, 0, 0, 0, 0, 0};

    floatx4 acc[9];
    #pragma unroll
    for (int q = 0; q < 9; ++q) acc[q] = (floatx4){0.f, 0.f, 0.f, 0.f};

    #pragma unroll
    for (int ph = 0; ph < 3; ++ph) {
        __syncthreads();
        const uint4* Wg = (const uint4*)(wtb + ph * 144 * 168);   // 3024 uint4
        uint4* Wl = (uint4*)Wt;
        #pragma unroll
        for (int q = 0; q < 12; ++q) {
            int idx = q * 256 + tid;
            if (idx < 3024) Wl[idx] = Wg[idx];
        }
        __syncthreads();

        const bf16* A = srcs[ph];
        short8 a[5];
        #pragma unroll
        for (int kt = 0; kt < 5; ++kt) {
            int k0 = kt * 32 + quad * 8;
            if (k0 < FF && row < NN)
                a[kt] = *(const short8*)((const short*)A + row * FF + k0);
            else
                a[kt] = zero8;
        }

        #pragma unroll
        for (int nt = 0; nt < 9; ++nt) {
            #pragma unroll
            for (int kt = 0; kt < 5; ++kt) {
                short8 b = *(const short8*)&Wt[(nt * 16 + m16) * 168 + kt * 32 + quad * 8];
                acc[nt] = __builtin_amdgcn_mfma_f32_16x16x32_bf16(a[kt], b, acc[nt], 0, 0, 0);
            }
        }
    }

    int rowc = rowBase + quad * 4;
    #pragma unroll
    for (int nt = 0; nt < 9; ++nt) {
        int col = nt * 16 + m16;
        float bs = bias[col];
        #pragma unroll
        for (int r = 0; r < 4; ++r) {
            int rr = rowc + r;
            if (rr < NN) out[rr * FF + col] = acc[nt][r] + bs;
        }
    }
}

// ---------------- launch ----------------

extern "C" void kernel_launch(void* const* d_in, const int* in_sizes, int n_in,
                              void* d_out, int out_size, void* d_ws, size_t ws_size,
                              hipStream_t stream) {
    int ix = -1, iei = -1, iew = -1, iwt = -1, ib = -1;
    for (int i = 0; i < n_in; ++i) {
        switch (in_sizes[i]) {
            case NN * FF:      if (ix  < 0) ix  = i; break;
            case 2 * EE:       if (iei < 0) iei = i; break;
            case EE:           if (iew < 0) iew = i; break;
            case 3 * FF * FF:  if (iwt < 0) iwt = i; break;
            case FF:           if (ib  < 0) ib  = i; break;
        }
    }
    if (ix < 0 || iei < 0 || iew < 0 || iwt < 0 || ib < 0) {
        ix = 0; iei = 1; iew = 2; iwt = 3; ib = 4;
    }
    const float* x    = (const float*)d_in[ix];
    const int*   ei   = (const int*)d_in[iei];
    const float* ew   = (const float*)d_in[iew];
    const float* wt   = (const float*)d_in[iwt];
    const float* bias = (const float*)d_in[ib];
    float* out = (float*)d_out;   // reference output dtype is float32

    char* p = (char*)d_ws;
    int*   cnt    = (int*)(p + 0);           // N ints
    int*   fill   = (int*)(p + 200000);      // N ints
    int*   rowptr = (int*)(p + 400000);      // N+1 ints
    float* dinv   = (float*)(p + 600016);    // N floats
    int2*  pairs  = (int2*)(p + 800016);     // E int2 (col, lap)
    bf16*  tx1    = (bf16*)(p + 7200016);
    bf16*  tx2    = (bf16*)(p + 21600016);
    short* wtb    = (short*)(p + 36000016);  // 3*144*168 shorts -> ends 36,145,168
    int*   bsum   = (int*)(p + 36200000);    // NBLK ints
    unsigned char* xq   = (unsigned char*)(p + 36300000);  // N*F fp8 -> ends 43,500,000
    unsigned char* tx1q = (unsigned char*)(p + 43600000);  // N*F fp8 -> ends 50,800,000
    bf16*  xb     = (bf16*)(p + 64800016);
    int*   eflag  = (int*)(p + 79200016);

    if (ws_size < 79200032) return;

    hipMemsetAsync(d_ws, 0, 400000, stream);  // cnt + fill

    int ewGrid16 = (NN * FF / 16 + 255) / 256;
    int spGrid   = (NN * 9 + 255) / 256;
    int gemmGrid = (NN + 63) / 64;
    int wGrid    = (3 * FF * 168 + 255) / 256;

    detect_k<<<1, 256, 0, stream>>>(ei, eflag);
    cvt_k<<<ewGrid16, 256, 0, stream>>>(x, xb, xq);
    cvtw_k<<<wGrid, 256, 0, stream>>>(wt, wtb);
    hist_k<<<(EE + 255) / 256, 256, 0, stream>>>(ei, cnt, eflag);
    dinv_k<<<(NN + 255) / 256, 256, 0, stream>>>(cnt, dinv);
    scan1_k<<<NBLK, 256, 0, stream>>>(cnt, rowptr, bsum);
    scan2_k<<<1, 256, 0, stream>>>(bsum, rowptr);
    scan3_k<<<NBLK, 256, 0, stream>>>(rowptr, bsum);
    scatter_k<<<(EE + 255) / 256, 256, 0, stream>>>(ei, ew, dinv, rowptr, fill, pairs, eflag);

    spmm_k<0><<<spGrid, 256, 0, stream>>>(xq, xb, rowptr, pairs, tx1, tx1q);
    spmm_k<1><<<spGrid, 256, 0, stream>>>(tx1q, xb, rowptr, pairs, tx2, (unsigned char*)0);
    gemm_fused<<<gemmGrid, 256, 0, stream>>>(xb, tx1, tx2, wtb, bias, out);
}

// Round 17
// 263.193 us; speedup vs baseline: 1.1764x; 1.0265x over previous
//
#include <hip/hip_runtime.h>
#include <hip/hip_bf16.h>

#define NN 50000
#define EE 800000
#define FF 144
#define NBLK 196   // ceil(NN/256)

typedef __hip_bfloat16 bf16;
typedef __attribute__((ext_vector_type(8))) short short8;
typedef __attribute__((ext_vector_type(4))) float floatx4;
typedef __attribute__((ext_vector_type(2))) float float2v;

__device__ inline float blo(unsigned x) { return __uint_as_float(x << 16); }
__device__ inline float bhi(unsigned x) { return __uint_as_float(x & 0xffff0000u); }

// ---- fp8 e4m3 pack/unpack (gfx950 OCP) ----
__device__ inline void dec4fma(float* a, float l, unsigned d) {
    float2v p0 = __builtin_amdgcn_cvt_pk_f32_fp8((int)d, false);
    float2v p1 = __builtin_amdgcn_cvt_pk_f32_fp8((int)d, true);
    a[0] = fmaf(l, p0.x, a[0]);
    a[1] = fmaf(l, p0.y, a[1]);
    a[2] = fmaf(l, p1.x, a[2]);
    a[3] = fmaf(l, p1.y, a[3]);
}
__device__ inline void fma16q(float* a, float l, uint4 u) {
    dec4fma(a + 0, l, u.x);
    dec4fma(a + 4, l, u.y);
    dec4fma(a + 8, l, u.z);
    dec4fma(a + 12, l, u.w);
}
__device__ inline unsigned enc4(float a, float b, float c, float d) {
    int w = __builtin_amdgcn_cvt_pk_fp8_f32(a, b, 0, false);
    w = __builtin_amdgcn_cvt_pk_fp8_f32(c, d, w, true);
    return (unsigned)w;
}

// ---------------- edge_index int64-layout detection ----------------

__global__ void detect_k(const int* __restrict__ ei, int* __restrict__ flag) {
    __shared__ int nz;
    if (threadIdx.x == 0) nz = 0;
    __syncthreads();
    if (ei[2 * threadIdx.x + 1] != 0) atomicAdd(&nz, 1);
    __syncthreads();
    if (threadIdx.x == 0) *flag = (nz == 0) ? 1 : 0;
}

__device__ inline void load_edge(const int* ei, int e, int flag, int& r, int& c) {
    if (flag) { r = ei[2 * e]; c = ei[2 * EE + 2 * e]; }
    else      { r = ei[e];     c = ei[EE + e]; }
}

// ---------------- x fp32 -> bf16 + fp8, 16 elements/thread ----------------

__global__ void cvt_k(const float* __restrict__ x, bf16* __restrict__ xb,
                      unsigned char* __restrict__ xq) {
    int t = blockIdx.x * 256 + threadIdx.x;
    if (t >= NN * FF / 16) return;
    const float4* xp = (const float4*)x + t * 4;
    float4 v0 = xp[0], v1 = xp[1], v2 = xp[2], v3 = xp[3];
    float f[16] = {v0.x, v0.y, v0.z, v0.w, v1.x, v1.y, v1.z, v1.w,
                   v2.x, v2.y, v2.z, v2.w, v3.x, v3.y, v3.z, v3.w};
    unsigned short hs[16];
    #pragma unroll
    for (int j = 0; j < 16; ++j) {
        bf16 b = (bf16)f[j];
        hs[j] = *(unsigned short*)&b;
    }
    uint4* xbq = (uint4*)xb + t * 2;
    xbq[0] = ((uint4*)hs)[0];
    xbq[1] = ((uint4*)hs)[1];
    uint4 q;
    q.x = enc4(f[0], f[1], f[2], f[3]);
    q.y = enc4(f[4], f[5], f[6], f[7]);
    q.z = enc4(f[8], f[9], f[10], f[11]);
    q.w = enc4(f[12], f[13], f[14], f[15]);
    ((uint4*)xq)[t] = q;
}

// ---------------- W fp32 (K,i,o) -> bf16 transposed padded image wtb[ph][o][i] ----------------

__global__ void cvtw_k(const float* __restrict__ wt, short* __restrict__ wtb) {
    int t = blockIdx.x * 256 + threadIdx.x;
    if (t >= 3 * FF * 168) return;
    int ph = t / (FF * 168);
    int rem = t - ph * FF * 168;
    int o = rem / 168;
    int i = rem - o * 168;
    short v = 0;
    if (i < FF) {
        bf16 b = (bf16)wt[ph * FF * FF + i * FF + o];
        v = *(const short*)&b;
    }
    wtb[t] = v;
}

// ---------------- graph preprocessing ----------------

__global__ void hist_k(const int* __restrict__ ei, int* __restrict__ cnt,
                       const int* __restrict__ flagp) {
    int flag = *flagp;
    int e = blockIdx.x * 256 + threadIdx.x;
    if (e >= EE) return;
    int r, c; load_edge(ei, e, flag, r, c);
    if (r != c) atomicAdd(&cnt[r], 1);
}

// ---------------- multi-block exclusive scan (dinv fused into phase 1) ----------------

__global__ void scan1_k(const int* __restrict__ cnt, int* __restrict__ rowptr,
                        int* __restrict__ bsum, float* __restrict__ dinv) {
    __shared__ int wsum[4], woff[4];
    int b = blockIdx.x, tid = threadIdx.x;
    int wv = tid >> 6, ln = tid & 63;
    int i = b * 256 + tid;
    int v = (i < NN) ? cnt[i] : 0;
    if (i < NN) dinv[i] = v > 0 ? rsqrtf((float)v) : 0.f;
    int x = v;
    #pragma unroll
    for (int off = 1; off < 64; off <<= 1) {
        int t = __shfl_up(x, off, 64);
        if (ln >= off) x += t;
    }
    if (ln == 63) wsum[wv] = x;
    __syncthreads();
    if (tid == 0) {
        int s = 0;
        #pragma unroll
        for (int j = 0; j < 4; ++j) { woff[j] = s; s += wsum[j]; }
        bsum[b] = s;
    }
    __syncthreads();
    if (i < NN) rowptr[i] = woff[wv] + (x - v);
}

__global__ void scan2_k(int* __restrict__ bsum, int* __restrict__ rowptr) {
    __shared__ int wsum[4], woff[4];
    int tid = threadIdx.x;
    int wv = tid >> 6, ln = tid & 63;
    int v = (tid < NBLK) ? bsum[tid] : 0;
    int x = v;
    #pragma unroll
    for (int off = 1; off < 64; off <<= 1) {
        int t = __shfl_up(x, off, 64);
        if (ln >= off) x += t;
    }
    if (ln == 63) wsum[wv] = x;
    __syncthreads();
    if (tid == 0) {
        int s = 0;
        #pragma unroll
        for (int j = 0; j < 4; ++j) { woff[j] = s; s += wsum[j]; }
        rowptr[NN] = s;
    }
    __syncthreads();
    if (tid < NBLK) bsum[tid] = woff[wv] + (x - v);
}

__global__ void scan3_k(int* __restrict__ rowptr, const int* __restrict__ bsum) {
    int b = blockIdx.x;
    int i = b * 256 + threadIdx.x;
    if (i < NN) rowptr[i] += bsum[b];
}

// ---------------- scatter: packed (col:16 | bf16(lap):16) single 4B word per edge ----------------
// N = 50000 < 2^16 so col fits low 16 bits; lap bf16 in high 16 decodes via bhi() for free.

__global__ void scatter_k(const int* __restrict__ ei, const float* __restrict__ w,
                          const float* __restrict__ dinv, const int* __restrict__ rowptr,
                          int* __restrict__ fill, unsigned* __restrict__ pairs,
                          const int* __restrict__ flagp) {
    int flag = *flagp;
    int e = blockIdx.x * 256 + threadIdx.x;
    if (e >= EE) return;
    int r, c; load_edge(ei, e, flag, r, c);
    if (r == c) return;
    int pos = rowptr[r] + atomicAdd(&fill[r], 1);
    float lap = -dinv[r] * dinv[c] * w[e];
    bf16 lb = (bf16)lap;
    pairs[pos] = (unsigned)c | ((unsigned)*(unsigned short*)&lb << 16);
}

// ---------------- SpMM fp8-gather: 9 threads/node, 16 fp8/edge, packed 4B edge stream ----------------

template <int MODE>
__global__ void spmm_k(const unsigned char* __restrict__ vq, const bf16* __restrict__ x0,
                       const int* __restrict__ rowptr, const unsigned* __restrict__ pairs,
                       bf16* __restrict__ y, unsigned char* __restrict__ yq) {
    int t = blockIdx.x * 256 + threadIdx.x;
    if (t >= NN * 9) return;
    int i = t / 9;
    int fo = (t - i * 9) * 16;
    const unsigned char* vp = vq + fo;

    float a[16];
    #pragma unroll
    for (int j = 0; j < 16; ++j) a[j] = 0.f;

    int s = rowptr[i], e = rowptr[i + 1];
    int p = s;
    for (; p + 1 < e; p += 2) {
        unsigned pr0 = pairs[p], pr1 = pairs[p + 1];
        uint4 u0 = *(const uint4*)(vp + (pr0 & 0xffffu) * FF);
        uint4 u1 = *(const uint4*)(vp + (pr1 & 0xffffu) * FF);
        fma16q(a, bhi(pr0), u0);
        fma16q(a, bhi(pr1), u1);
    }
    if (p < e) {
        unsigned pr = pairs[p];
        uint4 u = *(const uint4*)(vp + (pr & 0xffffu) * FF);
        fma16q(a, bhi(pr), u);
    }

    if (MODE == 1) {
        const uint4* xp = (const uint4*)((const unsigned short*)x0 + i * FF + fo);
        uint4 u0 = xp[0], u1 = xp[1];
        a[0]  = 2.f * a[0]  - blo(u0.x);  a[1]  = 2.f * a[1]  - bhi(u0.x);
        a[2]  = 2.f * a[2]  - blo(u0.y);  a[3]  = 2.f * a[3]  - bhi(u0.y);
        a[4]  = 2.f * a[4]  - blo(u0.z);  a[5]  = 2.f * a[5]  - bhi(u0.z);
        a[6]  = 2.f * a[6]  - blo(u0.w);  a[7]  = 2.f * a[7]  - bhi(u0.w);
        a[8]  = 2.f * a[8]  - blo(u1.x);  a[9]  = 2.f * a[9]  - bhi(u1.x);
        a[10] = 2.f * a[10] - blo(u1.y);  a[11] = 2.f * a[11] - bhi(u1.y);
        a[12] = 2.f * a[12] - blo(u1.z);  a[13] = 2.f * a[13] - bhi(u1.z);
        a[14] = 2.f * a[14] - blo(u1.w);  a[15] = 2.f * a[15] - bhi(u1.w);
    }

    unsigned short hs[16];
    #pragma unroll
    for (int j = 0; j < 16; ++j) {
        bf16 b = (bf16)a[j];
        hs[j] = *(unsigned short*)&b;
    }
    uint4* yp = (uint4*)((unsigned short*)y + i * FF + fo);
    yp[0] = ((uint4*)hs)[0];
    yp[1] = ((uint4*)hs)[1];

    if (MODE == 0) {
        uint4 q;
        q.x = enc4(a[0], a[1], a[2], a[3]);
        q.y = enc4(a[4], a[5], a[6], a[7]);
        q.z = enc4(a[8], a[9], a[10], a[11]);
        q.w = enc4(a[12], a[13], a[14], a[15]);
        *(uint4*)(yq + i * FF + fo) = q;
    }
}

// ---------------- fused MFMA GEMM (unchanged from r13-r16 passing version) ----------------

__global__ __launch_bounds__(256)
void gemm_fused(const bf16* __restrict__ A0, const bf16* __restrict__ A1,
                const bf16* __restrict__ A2, const short* __restrict__ wtb,
                const float* __restrict__ bias, float* __restrict__ out) {
    __shared__ __align__(16) short Wt[144 * 168];
    int tid = threadIdx.x;
    int wv = tid >> 6, ln = tid & 63;
    int m16 = ln & 15, quad = ln >> 4;
    int rowBase = blockIdx.x * 64 + wv * 16;
    int row = rowBase + m16;

    const bf16* const srcs[3] = {A0, A1, A2};
    const short8 zero8 = {0, 0, 0, 0, 0, 0, 0, 0};

    floatx4 acc[9];
    #pragma unroll
    for (int q = 0; q < 9; ++q) acc[q] = (floatx4){0.f, 0.f, 0.f, 0.f};

    #pragma unroll
    for (int ph = 0; ph < 3; ++ph) {
        __syncthreads();
        const uint4* Wg = (const uint4*)(wtb + ph * 144 * 168);   // 3024 uint4
        uint4* Wl = (uint4*)Wt;
        #pragma unroll
        for (int q = 0; q < 12; ++q) {
            int idx = q * 256 + tid;
            if (idx < 3024) Wl[idx] = Wg[idx];
        }
        __syncthreads();

        const bf16* A = srcs[ph];
        short8 a[5];
        #pragma unroll
        for (int kt = 0; kt < 5; ++kt) {
            int k0 = kt * 32 + quad * 8;
            if (k0 < FF && row < NN)
                a[kt] = *(const short8*)((const short*)A + row * FF + k0);
            else
                a[kt] = zero8;
        }

        #pragma unroll
        for (int nt = 0; nt < 9; ++nt) {
            #pragma unroll
            for (int kt = 0; kt < 5; ++kt) {
                short8 b = *(const short8*)&Wt[(nt * 16 + m16) * 168 + kt * 32 + quad * 8];
                acc[nt] = __builtin_amdgcn_mfma_f32_16x16x32_bf16(a[kt], b, acc[nt], 0, 0, 0);
            }
        }
    }

    int rowc = rowBase + quad * 4;
    #pragma unroll
    for (int nt = 0; nt < 9; ++nt) {
        int col = nt * 16 + m16;
        float bs = bias[col];
        #pragma unroll
        for (int r = 0; r < 4; ++r) {
            int rr = rowc + r;
            if (rr < NN) out[rr * FF + col] = acc[nt][r] + bs;
        }
    }
}

// ---------------- launch ----------------

extern "C" void kernel_launch(void* const* d_in, const int* in_sizes, int n_in,
                              void* d_out, int out_size, void* d_ws, size_t ws_size,
                              hipStream_t stream) {
    int ix = -1, iei = -1, iew = -1, iwt = -1, ib = -1;
    for (int i = 0; i < n_in; ++i) {
        switch (in_sizes[i]) {
            case NN * FF:      if (ix  < 0) ix  = i; break;
            case 2 * EE:       if (iei < 0) iei = i; break;
            case EE:           if (iew < 0) iew = i; break;
            case 3 * FF * FF:  if (iwt < 0) iwt = i; break;
            case FF:           if (ib  < 0) ib  = i; break;
        }
    }
    if (ix < 0 || iei < 0 || iew < 0 || iwt < 0 || ib < 0) {
        ix = 0; iei = 1; iew = 2; iwt = 3; ib = 4;
    }
    const float* x    = (const float*)d_in[ix];
    const int*   ei   = (const int*)d_in[iei];
    const float* ew   = (const float*)d_in[iew];
    const float* wt   = (const float*)d_in[iwt];
    const float* bias = (const float*)d_in[ib];
    float* out = (float*)d_out;   // reference output dtype is float32

    char* p = (char*)d_ws;
    int*      cnt    = (int*)(p + 0);           // N ints
    int*      fill   = (int*)(p + 200000);      // N ints
    int*      rowptr = (int*)(p + 400000);      // N+1 ints
    float*    dinv   = (float*)(p + 600016);    // N floats
    unsigned* pairs  = (unsigned*)(p + 800016); // E packed words (3.2 MB) -> ends 4,000,016
    bf16*     tx1    = (bf16*)(p + 7200016);
    bf16*     tx2    = (bf16*)(p + 21600016);
    short*    wtb    = (short*)(p + 36000016);  // 3*144*168 shorts
    int*      bsum   = (int*)(p + 36200000);    // NBLK ints
    unsigned char* xq   = (unsigned char*)(p + 36300000);  // N*F fp8
    unsigned char* tx1q = (unsigned char*)(p + 43600000);  // N*F fp8
    bf16*     xb     = (bf16*)(p + 64800016);
    int*      eflag  = (int*)(p + 79200016);

    if (ws_size < 79200032) return;

    hipMemsetAsync(d_ws, 0, 400000, stream);  // cnt + fill

    int ewGrid16 = (NN * FF / 16 + 255) / 256;
    int spGrid   = (NN * 9 + 255) / 256;
    int gemmGrid = (NN + 63) / 64;
    int wGrid    = (3 * FF * 168 + 255) / 256;

    detect_k<<<1, 256, 0, stream>>>(ei, eflag);
    cvt_k<<<ewGrid16, 256, 0, stream>>>(x, xb, xq);
    cvtw_k<<<wGrid, 256, 0, stream>>>(wt, wtb);
    hist_k<<<(EE + 255) / 256, 256, 0, stream>>>(ei, cnt, eflag);
    scan1_k<<<NBLK, 256, 0, stream>>>(cnt, rowptr, bsum, dinv);
    scan2_k<<<1, 256, 0, stream>>>(bsum, rowptr);
    scan3_k<<<NBLK, 256, 0, stream>>>(rowptr, bsum);
    scatter_k<<<(EE + 255) / 256, 256, 0, stream>>>(ei, ew, dinv, rowptr, fill, pairs, eflag);

    spmm_k<0><<<spGrid, 256, 0, stream>>>(xq, xb, rowptr, pairs, tx1, tx1q);
    spmm_k<1><<<spGrid, 256, 0, stream>>>(tx1q, xb, rowptr, pairs, tx2, (unsigned char*)0);
    gemm_fused<<<gemmGrid, 256, 0, stream>>>(xb, tx1, tx2, wtb, bias, out);
}